// Round 2
// baseline (160.027 us; speedup 1.0000x reference)
//
#include <hip/hip_runtime.h>
#include <math.h>

#define NSAMP 4
#define NB 64
#define LVOL (64*64*64)
#define PADR 67           // rows: bins -1..65 (+1 offset)
#define PADC 68           // col stride; cols -1..65 used
#define PADSZ (PADR*PADC)

// ---- float <-> order-preserving uint (for atomic min/max on floats) ----
__device__ __forceinline__ unsigned f2ord(float f){
  unsigned u = __float_as_uint(f);
  return (u & 0x80000000u) ? ~u : (u | 0x80000000u);
}
__device__ __forceinline__ float ord2f(unsigned u){
  unsigned v = (u & 0x80000000u) ? (u ^ 0x80000000u) : ~u;
  return __uint_as_float(v);
}

// ---- kernel 0: init workspace (min/max slots + hist + ratio zeros) ----
__global__ void k_init(unsigned* __restrict__ mm, float* __restrict__ zbuf, int nz){
  int i = blockIdx.x * blockDim.x + threadIdx.x;
  if (i < nz) zbuf[i] = 0.0f;
  if (i < NSAMP * 4) mm[i] = (i & 1) ? 0u : 0xFFFFFFFFu; // even=min(init MAX), odd=max(init 0)
}

// ---- kernel 1: per-sample min/max of target and source ----
__global__ __launch_bounds__(256) void k_minmax(const float* __restrict__ tgt,
                                                const float* __restrict__ src,
                                                unsigned* __restrict__ mm){
  const int n = blockIdx.x >> 8;      // 256 blocks per sample
  const int chunk = blockIdx.x & 255; // 1024 elems per block
  const float4* t4 = (const float4*)(tgt + (size_t)n * LVOL) + (size_t)chunk * 256;
  const float4* s4 = (const float4*)(src + (size_t)n * LVOL) + (size_t)chunk * 256;
  float4 a = t4[threadIdx.x];
  float4 b = s4[threadIdx.x];
  float tmn = fminf(fminf(a.x, a.y), fminf(a.z, a.w));
  float tmx = fmaxf(fmaxf(a.x, a.y), fmaxf(a.z, a.w));
  float smn = fminf(fminf(b.x, b.y), fminf(b.z, b.w));
  float smx = fmaxf(fmaxf(b.x, b.y), fmaxf(b.z, b.w));
  for (int off = 32; off; off >>= 1){
    tmn = fminf(tmn, __shfl_down(tmn, off));
    tmx = fmaxf(tmx, __shfl_down(tmx, off));
    smn = fminf(smn, __shfl_down(smn, off));
    smx = fmaxf(smx, __shfl_down(smx, off));
  }
  __shared__ float red[4][4];
  const int wave = threadIdx.x >> 6, lane = threadIdx.x & 63;
  if (lane == 0){ red[wave][0]=tmn; red[wave][1]=tmx; red[wave][2]=smn; red[wave][3]=smx; }
  __syncthreads();
  if (threadIdx.x == 0){
    for (int w = 1; w < 4; ++w){
      tmn = fminf(tmn, red[w][0]); tmx = fmaxf(tmx, red[w][1]);
      smn = fminf(smn, red[w][2]); smx = fmaxf(smx, red[w][3]);
    }
    atomicMin(&mm[n*4+0], f2ord(tmn));
    atomicMax(&mm[n*4+1], f2ord(tmx));
    atomicMin(&mm[n*4+2], f2ord(smn));
    atomicMax(&mm[n*4+3], f2ord(smx));
  }
}

// ---- kernel 2: joint histogram via sparse 4x4 B-spline scatter ----
// Branch-free: guard-padded LDS hist absorbs bins -1,64,65; closed-form
// B-spline weights from fractional part (partition of unity for w2).
__device__ __forceinline__ void scatter16(float* sh, float u, float v){
  float fu = floorf(u), fv = floorf(v);
  int iu = (int)fu, iv = (int)fv;
  float f = u - fu, g = 1.0f - f;
  float wu0 = g*g*g*(1.0f/6.0f);
  float wu3 = f*f*f*(1.0f/6.0f);
  float wu1 = (2.0f/3.0f) - f*f + 0.5f*f*f*f;
  float wu2 = 1.0f - wu0 - wu1 - wu3;
  float p = v - fv, q = 1.0f - p;
  float wv0 = q*q*q*(1.0f/6.0f);
  float wv3 = p*p*p*(1.0f/6.0f);
  float wv1 = (2.0f/3.0f) - p*p + 0.5f*p*p*p;
  float wv2 = 1.0f - wv0 - wv1 - wv3;
  float wu[4] = {wu0, wu1, wu2, wu3};
  #pragma unroll
  for (int a = 0; a < 4; ++a){
    int ro = (iu + a) * PADC + iv;   // padded row index = bin+1 folded in
    float wa = wu[a];
    atomicAdd(&sh[ro + 0], wa * wv0);
    atomicAdd(&sh[ro + 1], wa * wv1);
    atomicAdd(&sh[ro + 2], wa * wv2);
    atomicAdd(&sh[ro + 3], wa * wv3);
  }
}

__global__ __launch_bounds__(256) void k_hist(const float* __restrict__ tgt,
                                              const float* __restrict__ src,
                                              const unsigned* __restrict__ mm,
                                              float* __restrict__ hist){
  const int n = blockIdx.x >> 8;      // 256 chunks per sample
  const int chunk = blockIdx.x & 255; // 1024 elems per block
  __shared__ float sh[PADSZ];
  for (int i = threadIdx.x; i < PADSZ; i += 256) sh[i] = 0.0f;
  const float tmn = ord2f(mm[n*4+0]);
  const float tmx = ord2f(mm[n*4+1]);
  const float smn = ord2f(mm[n*4+2]);
  const float smx = ord2f(mm[n*4+3]);
  const float st = (float)NB / (tmx - tmn + 1e-12f);
  const float ss = (float)NB / (smx - smn + 1e-12f);
  const size_t base = (size_t)n * LVOL + (size_t)chunk * 1024;
  float4 a = ((const float4*)(tgt + base))[threadIdx.x];
  float4 b = ((const float4*)(src + base))[threadIdx.x];
  __syncthreads();
  scatter16(sh, (a.x - tmn) * st, (b.x - smn) * ss);
  scatter16(sh, (a.y - tmn) * st, (b.y - smn) * ss);
  scatter16(sh, (a.z - tmn) * st, (b.z - smn) * ss);
  scatter16(sh, (a.w - tmn) * st, (b.w - smn) * ss);
  __syncthreads();
  float* gh = hist + n * NB * NB;
  for (int i = threadIdx.x; i < NB * NB; i += 256){
    int r = i >> 6, c = i & 63;
    float v = sh[(r + 1) * PADC + (c + 1)];
    if (v != 0.0f) atomicAdd(&gh[i], v);
  }
}

// ---- kernel 3: per-sample entropies and NMI ratio ----
__global__ __launch_bounds__(256) void k_entropy(const float* __restrict__ hist,
                                                 float* __restrict__ ratio){
  const int n = blockIdx.x;
  const float* h = hist + n * NB * NB;
  __shared__ float rowsum[NB], colsum[NB];
  __shared__ float wr1[4], wr2[4];
  __shared__ float S_sh;
  if (threadIdx.x < NB){ rowsum[threadIdx.x] = 0.0f; colsum[threadIdx.x] = 0.0f; }
  __syncthreads();
  const int r  = threadIdx.x >> 2;        // each thread: 16 contiguous elems of one row
  const int c0 = (threadIdx.x & 3) * 16;
  float hv[16];
  float rsum = 0.0f;
  #pragma unroll
  for (int k = 0; k < 16; ++k){ hv[k] = h[r * NB + c0 + k]; rsum += hv[k]; }
  atomicAdd(&rowsum[r], rsum);
  #pragma unroll
  for (int k = 0; k < 16; ++k) atomicAdd(&colsum[c0 + k], hv[k]);
  // total sum
  float part = rsum;
  for (int off = 32; off; off >>= 1) part += __shfl_down(part, off);
  if ((threadIdx.x & 63) == 0) wr1[threadIdx.x >> 6] = part;
  __syncthreads();   // also makes rowsum/colsum atomics visible
  if (threadIdx.x == 0) S_sh = wr1[0] + wr1[1] + wr1[2] + wr1[3];
  __syncthreads();
  const float invS = 1.0f / S_sh;
  // joint entropy
  float ej = 0.0f;
  #pragma unroll
  for (int k = 0; k < 16; ++k){
    float p = hv[k] * invS;
    ej -= p * logf(p + 1e-12f);
  }
  for (int off = 32; off; off >>= 1) ej += __shfl_down(ej, off);
  if ((threadIdx.x & 63) == 0) wr2[threadIdx.x >> 6] = ej;
  // marginal entropies (wave 0 only; 64 lanes = 64 bins)
  float em = 0.0f;
  if (threadIdx.x < NB){
    float pt = rowsum[threadIdx.x] * invS;
    float ps = colsum[threadIdx.x] * invS;
    em = -pt * logf(pt + 1e-12f) - ps * logf(ps + 1e-12f);
    for (int off = 32; off; off >>= 1) em += __shfl_down(em, off);
  }
  __syncthreads();
  if (threadIdx.x == 0){
    float EJ = wr2[0] + wr2[1] + wr2[2] + wr2[3];
    ratio[n] = em / EJ;   // (Ht + Hs) / Hj
  }
}

// ---- kernel 4: final -mean over samples ----
__global__ void k_final(const float* __restrict__ ratio, float* __restrict__ out){
  if (threadIdx.x == 0)
    out[0] = -0.25f * (ratio[0] + ratio[1] + ratio[2] + ratio[3]);
}

extern "C" void kernel_launch(void* const* d_in, const int* in_sizes, int n_in,
                              void* d_out, int out_size, void* d_ws, size_t ws_size,
                              hipStream_t stream){
  const float* tgt = (const float*)d_in[0];
  const float* src = (const float*)d_in[1];
  float* out = (float*)d_out;
  // workspace layout: [0..64) uint minmax (16 used) | [256..) hist 4*4096 f32 | ratio 4 f32
  unsigned* mm = (unsigned*)d_ws;
  float* hist  = (float*)((char*)d_ws + 256);
  float* ratio = hist + NSAMP * NB * NB;
  const int nz = NSAMP * NB * NB + NSAMP;   // hist + ratio contiguous
  k_init<<<(nz + 255) / 256, 256, 0, stream>>>(mm, hist, nz);
  k_minmax<<<NSAMP * 256, 256, 0, stream>>>(tgt, src, mm);
  k_hist<<<NSAMP * 256, 256, 0, stream>>>(tgt, src, mm, hist);
  k_entropy<<<NSAMP, 256, 0, stream>>>(hist, ratio);
  k_final<<<1, 64, 0, stream>>>(ratio, out);
}

// Round 3
// 97.218 us; speedup vs baseline: 1.6461x; 1.6461x over previous
//
#include <hip/hip_runtime.h>
#include <math.h>

#define NSAMP 4
#define NB 64
#define LVOL (64*64*64)
#define PADR 68                 // rows 0..67 = bins -1..66 (guards for iu in [0,64])
#define KBLK 8                  // 8 k-blocks x 32 voxels = 256 voxels per iter
#define TILEB (PADR*64)         // bytes per k-block: 68 rows * 32 k * 2B = 4352
#define ABYTES (KBLK*TILEB)     // 34816 bytes per matrix
// XOR-swizzle byte-addr bits 4..6 by row bits 1..3: makes the strided
// fragment reads (16 lanes, 64B row stride) conflict-free. Applied
// IDENTICALLY at scatter-write and frag-read; bijective (row-bit0 flip
// driven by row-bit3 is an involution; rows<=67 stay in range).
#define SWZ(a,row) ((a) ^ ((((row)>>1)&7)<<4))

typedef __attribute__((ext_vector_type(8))) short bf16x8;
typedef __attribute__((ext_vector_type(4))) float f32x4;

__device__ __forceinline__ unsigned short f2bf(float x){  // RNE f32->bf16
  unsigned u = __float_as_uint(x);
  return (unsigned short)((u + 0x7FFFu + ((u >> 16) & 1u)) >> 16);
}

// ---- kernel 1: per-chunk min/max partials (non-atomic) ----
__global__ __launch_bounds__(256) void k_minmax(const float* __restrict__ tgt,
                                                const float* __restrict__ src,
                                                float4* __restrict__ mmp){
  const int n = blockIdx.x >> 5, chunk = blockIdx.x & 31;   // 32 chunks/sample
  const float4* t4 = (const float4*)(tgt + (size_t)n * LVOL) + (size_t)chunk * 2048;
  const float4* s4 = (const float4*)(src + (size_t)n * LVOL) + (size_t)chunk * 2048;
  float tmn = INFINITY, tmx = -INFINITY, smn = INFINITY, smx = -INFINITY;
  for (int i = threadIdx.x; i < 2048; i += 256){
    float4 a = t4[i];
    tmn = fminf(tmn, fminf(fminf(a.x, a.y), fminf(a.z, a.w)));
    tmx = fmaxf(tmx, fmaxf(fmaxf(a.x, a.y), fmaxf(a.z, a.w)));
    float4 b = s4[i];
    smn = fminf(smn, fminf(fminf(b.x, b.y), fminf(b.z, b.w)));
    smx = fmaxf(smx, fmaxf(fmaxf(b.x, b.y), fmaxf(b.z, b.w)));
  }
  for (int off = 32; off; off >>= 1){
    tmn = fminf(tmn, __shfl_down(tmn, off));
    tmx = fmaxf(tmx, __shfl_down(tmx, off));
    smn = fminf(smn, __shfl_down(smn, off));
    smx = fmaxf(smx, __shfl_down(smx, off));
  }
  __shared__ float red[4][4];
  const int wave = threadIdx.x >> 6, lane = threadIdx.x & 63;
  if (lane == 0){ red[wave][0]=tmn; red[wave][1]=tmx; red[wave][2]=smn; red[wave][3]=smx; }
  __syncthreads();
  if (threadIdx.x == 0){
    for (int w = 1; w < 4; ++w){
      tmn = fminf(tmn, red[w][0]); tmx = fmaxf(tmx, red[w][1]);
      smn = fminf(smn, red[w][2]); smx = fmaxf(smx, red[w][3]);
    }
    mmp[blockIdx.x] = make_float4(tmn, tmx, smn, smx);
  }
}

// ---- kernel 2: joint histogram as bf16 MFMA GEMM ----
// hist[i][j] = sum_l Wt[i,l]*Ws[j,l]; A=Wt[64 x K], B^T=Ws[64 x K] (gemm_bt).
// Per 256-voxel iter: zero LDS tiles, scatter 4 bf16 weights per voxel per
// side (voxel owns its K-column -> non-atomic), 32 MFMAs over 8 k-blocks.
__global__ __launch_bounds__(256) void k_hist(const float* __restrict__ tgt,
                                              const float* __restrict__ src,
                                              const float4* __restrict__ mmp,
                                              float* __restrict__ partial, int wps){
  __shared__ __align__(16) char lds[2 * ABYTES];   // A then B
  __shared__ float mmsh[4];
  const int tid = threadIdx.x;
  const int n = blockIdx.x / wps, wg = blockIdx.x % wps;
  // reduce the 32 min/max partials for this sample
  if (tid < 32){
    float4 v = mmp[n * 32 + tid];
    for (int off = 16; off; off >>= 1){
      v.x = fminf(v.x, __shfl_down(v.x, off));
      v.y = fmaxf(v.y, __shfl_down(v.y, off));
      v.z = fminf(v.z, __shfl_down(v.z, off));
      v.w = fmaxf(v.w, __shfl_down(v.w, off));
    }
    if (tid == 0){ mmsh[0]=v.x; mmsh[1]=v.y; mmsh[2]=v.z; mmsh[3]=v.w; }
  }
  __syncthreads();
  const float tmn = mmsh[0], smn = mmsh[2];
  const float st = (float)NB / (mmsh[1] - tmn + 1e-12f);
  const float ss = (float)NB / (mmsh[3] - smn + 1e-12f);
  const int vper = LVOL / wps;
  const size_t vbase = (size_t)n * LVOL + (size_t)wg * vper;
  const int iters = vper >> 8;
  const int kb_ = tid >> 5, k2 = tid & 31;          // voxel -> (kblock, k-in-block)
  const int lane = tid & 63, wv = tid >> 6;
  const int r = lane & 15, g = lane >> 4;
  // fragment read offsets (swizzled, constant across kb)
  const int arow = 1 + 16 * wv + r;                  // wave wv owns C rows 16wv..16wv+15
  const int sa = SWZ(arow * 64 + g * 16, arow);
  int sb[4];
  #pragma unroll
  for (int ct = 0; ct < 4; ++ct){
    int br = 1 + 16 * ct + r;
    sb[ct] = ABYTES + SWZ(br * 64 + g * 16, br);
  }
  f32x4 acc[4];
  #pragma unroll
  for (int ct = 0; ct < 4; ++ct) acc[ct] = (f32x4){0.f, 0.f, 0.f, 0.f};

  for (int it = 0; it < iters; ++it){
    __syncthreads();                                  // prev iter reads done
    int4 zz = make_int4(0, 0, 0, 0);
    #pragma unroll
    for (int i = 0; i < 17; ++i) ((int4*)lds)[tid + i * 256] = zz;  // 69632B
    __syncthreads();
    const float tv = tgt[vbase + (size_t)it * 256 + tid];
    const float sv = src[vbase + (size_t)it * 256 + tid];
    {
      float u = (tv - tmn) * st;
      float fu = floorf(u); int iu = (int)fu; float f = u - fu, q = 1.f - f;
      float w0 = q*q*q*(1.f/6.f), w3 = f*f*f*(1.f/6.f);
      float w1 = (2.f/3.f) - f*f + 0.5f*f*f*f, w2 = 1.f - w0 - w1 - w3;
      float w[4] = {w0, w1, w2, w3};
      const int base = kb_ * TILEB + k2 * 2;
      #pragma unroll
      for (int a = 0; a < 4; ++a){
        int row = iu + a;                             // lds row = bin+1
        *(unsigned short*)(lds + SWZ(base + row * 64, row)) = f2bf(w[a]);
      }
    }
    {
      float u = (sv - smn) * ss;
      float fu = floorf(u); int iu = (int)fu; float f = u - fu, q = 1.f - f;
      float w0 = q*q*q*(1.f/6.f), w3 = f*f*f*(1.f/6.f);
      float w1 = (2.f/3.f) - f*f + 0.5f*f*f*f, w2 = 1.f - w0 - w1 - w3;
      float w[4] = {w0, w1, w2, w3};
      const int base = ABYTES + kb_ * TILEB + k2 * 2;
      #pragma unroll
      for (int a = 0; a < 4; ++a){
        int row = iu + a;
        *(unsigned short*)(lds + SWZ(base + row * 64, row)) = f2bf(w[a]);
      }
    }
    __syncthreads();
    #pragma unroll
    for (int kb = 0; kb < KBLK; ++kb){
      const char* p = lds + kb * TILEB;
      bf16x8 af = *(const bf16x8*)(p + sa);
      #pragma unroll
      for (int ct = 0; ct < 4; ++ct){
        bf16x8 bf = *(const bf16x8*)(p + sb[ct]);
        acc[ct] = __builtin_amdgcn_mfma_f32_16x16x32_bf16(af, bf, acc[ct], 0, 0, 0);
      }
    }
  }
  // epilogue: C/D map col=lane&15, row=(lane>>4)*4+e  (m89-verified)
  float* P = partial + (size_t)blockIdx.x * 4096;
  #pragma unroll
  for (int ct = 0; ct < 4; ++ct)
    #pragma unroll
    for (int e = 0; e < 4; ++e)
      P[(16 * wv + g * 4 + e) * 64 + 16 * ct + r] = acc[ct][e];
}

// ---- kernel 3: reduce per-WG partials into hist ----
__global__ __launch_bounds__(256) void k_reduce(const float* __restrict__ P,
                                                float* __restrict__ hist, int wps){
  const int i = blockIdx.x * 256 + threadIdx.x;       // 0..16383
  const int n = i >> 12, bin = i & 4095;
  const float* p = P + ((size_t)n * wps) * 4096 + bin;
  float s = 0.f;
  for (int w = 0; w < wps; ++w) s += p[(size_t)w * 4096];
  hist[i] = s;
}

// ---- kernel 4: entropies + NMI for all 4 samples + final mean (1 block) ----
__global__ __launch_bounds__(256) void k_tail(const float* __restrict__ hist,
                                              float* __restrict__ out){
  __shared__ float rowsum[NB], colsum[NB], wr1[4], wr2[4];
  __shared__ float S_sh;
  const int tid = threadIdx.x;
  float total = 0.f;
  for (int n = 0; n < NSAMP; ++n){
    if (tid < NB){ rowsum[tid] = 0.f; colsum[tid] = 0.f; }
    __syncthreads();
    const float* h = hist + n * 4096;
    const int r = tid >> 2, c0 = (tid & 3) * 16;
    float hv[16];
    float rsum = 0.f;
    #pragma unroll
    for (int k = 0; k < 16; ++k){ hv[k] = h[r * 64 + c0 + k]; rsum += hv[k]; }
    atomicAdd(&rowsum[r], rsum);
    #pragma unroll
    for (int k = 0; k < 16; ++k) atomicAdd(&colsum[c0 + k], hv[k]);
    float part = rsum;
    for (int off = 32; off; off >>= 1) part += __shfl_down(part, off);
    if ((tid & 63) == 0) wr1[tid >> 6] = part;
    __syncthreads();
    if (tid == 0) S_sh = wr1[0] + wr1[1] + wr1[2] + wr1[3];
    __syncthreads();
    const float invS = 1.f / S_sh;
    float ej = 0.f;
    #pragma unroll
    for (int k = 0; k < 16; ++k){
      float p = hv[k] * invS;
      ej -= p * logf(p + 1e-12f);
    }
    for (int off = 32; off; off >>= 1) ej += __shfl_down(ej, off);
    if ((tid & 63) == 0) wr2[tid >> 6] = ej;
    float em = 0.f;
    if (tid < NB){
      float pt = rowsum[tid] * invS;
      float ps = colsum[tid] * invS;
      em = -pt * logf(pt + 1e-12f) - ps * logf(ps + 1e-12f);
      for (int off = 32; off; off >>= 1) em += __shfl_down(em, off);
    }
    __syncthreads();
    if (tid == 0){
      float EJ = wr2[0] + wr2[1] + wr2[2] + wr2[3];
      total += em / EJ;
    }
    __syncthreads();    // protect shared reuse before next sample
  }
  if (tid == 0) out[0] = -0.25f * total;
}

extern "C" void kernel_launch(void* const* d_in, const int* in_sizes, int n_in,
                              void* d_out, int out_size, void* d_ws, size_t ws_size,
                              hipStream_t stream){
  const float* tgt = (const float*)d_in[0];
  const float* src = (const float*)d_in[1];
  float* out = (float*)d_out;
  char* ws = (char*)d_ws;
  // ws layout: [0: mmp 128*float4 = 2KB][2048: hist 64KB][67584: partials]
  float4* mmp = (float4*)ws;
  float* hist = (float*)(ws + 2048);
  float* P    = (float*)(ws + 2048 + 65536);
  const size_t base = 2048 + 65536;
  int wps = 128;                                      // workgroups per sample
  while (wps > 1 && base + (size_t)NSAMP * wps * 4096 * sizeof(float) > ws_size)
    wps >>= 1;
  k_minmax<<<128, 256, 0, stream>>>(tgt, src, mmp);
  k_hist<<<NSAMP * wps, 256, 0, stream>>>(tgt, src, mmp, P, wps);
  k_reduce<<<64, 256, 0, stream>>>(P, hist, wps);
  k_tail<<<1, 256, 0, stream>>>(hist, out);
}